// Round 7
// baseline (207.416 us; speedup 1.0000x reference)
//
#include <hip/hip_runtime.h>

// CRF forward loss, MI355X — exp-domain, barrier-free SPSC pipeline.
// Grid 256 = (batch 128) x (chain 2). Block 256 = 4 waves:
//   wave 0 = chain (owns the serial recurrence),
//   waves 1-3 = builders (16 score rows each): load -> exp2 -> LDS E-ring.
// Ring: 5 slots x 9216 B (E matrices, f32). SPSC flags: builders publish
// slot t after lgkmcnt(0); chain publishes progress for back-pressure.
// Chain step: u_new[j] = sum_i E[i][j] * u_i via 48 readlane+fmac.

constexpr int SEQ = 256;
constexpr int NTAG = 48;
constexpr int START_TAG = 46;
constexpr int END_TAG = 47;
constexpr float L2E = 1.4426950408889634f; // log2(e)
constexpr float LN2 = 0.6931471805599453f;
constexpr int NBUF = 5;
constexpr int SLAB = NTAG * NTAG * 4;      // 9216 B
constexpr int FLAG_OFF = NBUF * SLAB;      // flags: [0..2]=builders, [3]=chain

__device__ __forceinline__ float fexp2(float x) { return __builtin_amdgcn_exp2f(x); }
__device__ __forceinline__ float flog2(float x) { return __builtin_amdgcn_logf(x); }
__device__ __forceinline__ float rlane(float v, int l) {
    return __uint_as_float(__builtin_amdgcn_readlane(__float_as_uint(v), l));
}

__global__ __launch_bounds__(256, 1)
void crf_chain_kernel(const float* __restrict__ S,
                      const void* __restrict__ tgtv,
                      const void* __restrict__ mskv,
                      float* __restrict__ ws)
{
    __shared__ __align__(16) unsigned char lds[NBUF * SLAB + 64];
    volatile int* flags = (volatile int*)(lds + FLAG_OFF);

    const int bid  = blockIdx.x;
    const int b    = bid & 127;          // batch
    const int tagc = bid >> 7;           // 0: partition, 1: tag_partition
    const int tid  = threadIdx.x;
    const int k    = tid >> 6;           // wave id: 0=chain, 1..3=builders
    const int j    = tid & 63;           // lane
    const bool jok = (j < NTAG);
    const int jj   = jok ? j : 0;

    // dtype detection: packed bool (1B) vs int32 (mask[0..3] all true)
    const bool pack8 = (((const int*)mskv)[0] != 1);
    const unsigned char* msk8  = (const unsigned char*)mskv;
    const int*           msk32 = (const int*)mskv;
    const unsigned char* tgt8  = (const unsigned char*)tgtv;
    const int*           tgt32 = (const int*)tgtv;

    auto ldtgt = [&](int t) -> int {
        int ti = (b * SEQ + t) * NTAG + jj;
        return pack8 ? (int)tgt8[ti] : tgt32[ti];
    };

    // sequence length via ballots (each wave computes its own copy)
    int len = 0;
    #pragma unroll
    for (int r = 0; r < 4; ++r) {
        int idx = b * SEQ + r * 64 + j;
        int mm = pack8 ? (msk8[idx] != 0) : (msk32[idx] != 0);
        len += (int)__popcll(__ballot(mm));
    }

    if (tid < 4) ((int*)(lds + FLAG_OFF))[tid] = 0;   // zero SPSC flags
    __syncthreads();                                   // only barrier in kernel

    const size_t sbf = (size_t)b * SEQ * NTAG * NTAG;

    if (k == 0) {
        // ================= CHAIN WAVE =================
        float st0 = S[sbf + START_TAG * NTAG + jj] * L2E;
        if (!jok) st0 = -1e30f;
        float M0 = st0;
        #pragma unroll
        for (int off = 1; off < 64; off <<= 1) M0 = fmaxf(M0, __shfl_xor(M0, off));
        float u = jok ? fexp2(st0 - M0) : 0.0f;
        if (tagc && jok) { if (ldtgt(0)) u = 0.0f; }
        float Mg = M0;

        auto poll = [&](int t) {
            while (true) {
                int f0 = flags[0], f1 = flags[1], f2 = flags[2];
                if (f0 >= t && f1 >= t && f2 >= t) break;
                __builtin_amdgcn_s_sleep(2);
            }
            asm volatile("" ::: "memory");   // no load hoisting above handshake
        };
        auto eload = [&](float (&E)[48], int tau) {
            const float* p = (const float*)(lds + (tau % NBUF) * SLAB) + jj;
            #pragma unroll
            for (int i = 0; i < 48; ++i) E[i] = p[i * 48];
        };

        float EA[48], EB[48];
        int tvA = 0, tvB = 0;
        poll(1);
        eload(EA, 1);
        if (tagc) tvA = ldtgt(1);

        auto iter = [&](float (&Eu)[48], float (&Ef)[48], int& tvU, int& tvF, int t) {
            if (t + 1 < len) {               // prefetch next E column + target
                poll(t + 1);
                eload(Ef, t + 1);
                if (tagc) tvF = ldtgt(t + 1);
            }
            float a0 = 0.f, a1 = 0.f, a2 = 0.f, a3 = 0.f;
            #pragma unroll
            for (int i = 0; i < 48; i += 4) {
                a0 = fmaf(Eu[i],     rlane(u, i),     a0);
                a1 = fmaf(Eu[i + 1], rlane(u, i + 1), a1);
                a2 = fmaf(Eu[i + 2], rlane(u, i + 2), a2);
                a3 = fmaf(Eu[i + 3], rlane(u, i + 3), a3);
            }
            float un = (a0 + a1) + (a2 + a3);
            if (tagc && tvU) un = 0.0f;      // target mask: exact zero
            if (!jok) un = 0.0f;
            if ((t & 7) == 0) {              // renorm: max(u) -> [0.5,1)
                float mx = un;
                #pragma unroll
                for (int off = 1; off < 64; off <<= 1) mx = fmaxf(mx, __shfl_xor(mx, off));
                int ex = (int)((__float_as_uint(mx) >> 23) & 0xFF) - 126;
                un = ldexpf(un, -ex);
                Mg += (float)ex;
            }
            u = un;
            if (j == 0) flags[3] = t;        // progress (back-pressure release)
        };

        int t = 1;
        while (t < len) {
            iter(EA, EB, tvA, tvB, t);
            ++t; if (t >= len) break;
            iter(EB, EA, tvB, tvA, t);
            ++t;
        }

        if (j == END_TAG) {
            float r = (Mg + flog2(u)) * LN2;  // back to ln domain
            if (tagc) r = (u == 0.0f) ? 0.0f : -r;
            ws[bid] = r;
        }
    } else {
        // ================= BUILDER WAVES (k = 1..3) =================
        const int w = k - 1;                  // rows 16w .. 16w+15
        const unsigned char* Gb = (const unsigned char*)S + sbf * 4
                                + 3072 * w + 16 * j;
        float4 r0, r1, r2;
        auto bload = [&](int t) {
            const float4* p = (const float4*)(Gb + (size_t)t * SLAB);
            r0 = p[0]; r1 = p[64]; r2 = p[128];   // +0 / +1024B / +2048B
        };
        bload(1);
        for (int t = 1; t < len; ++t) {
            float4 e0, e1, e2;
            e0.x = fexp2(r0.x * L2E); e0.y = fexp2(r0.y * L2E);
            e0.z = fexp2(r0.z * L2E); e0.w = fexp2(r0.w * L2E);
            e1.x = fexp2(r1.x * L2E); e1.y = fexp2(r1.y * L2E);
            e1.z = fexp2(r1.z * L2E); e1.w = fexp2(r1.w * L2E);
            e2.x = fexp2(r2.x * L2E); e2.y = fexp2(r2.y * L2E);
            e2.z = fexp2(r2.z * L2E); e2.w = fexp2(r2.w * L2E);
            if (t + 1 < len) bload(t + 1);    // issue early; lands during wait
            while (flags[3] < t - 4)          // ring-5 back-pressure
                __builtin_amdgcn_s_sleep(2);
            asm volatile("" ::: "memory");
            unsigned char* dst = lds + (t % NBUF) * SLAB + 3072 * w + 16 * j;
            *(float4*)(dst)        = e0;
            *(float4*)(dst + 1024) = e1;
            *(float4*)(dst + 2048) = e2;
            asm volatile("s_waitcnt lgkmcnt(0)" ::: "memory");  // data before flag
            if (j == 0) flags[w] = t;         // publish slot t
        }
    }
}

__global__ void crf_reduce_kernel(const float* __restrict__ ws, float* __restrict__ out)
{
    int l = threadIdx.x;                      // 64 threads
    float v = (ws[l] + ws[l + 64]) + (ws[l + 128] + ws[l + 192]);
    #pragma unroll
    for (int off = 32; off > 0; off >>= 1) v += __shfl_down(v, off);
    if (l == 0) out[0] = v;
}

extern "C" void kernel_launch(void* const* d_in, const int* in_sizes, int n_in,
                              void* d_out, int out_size, void* d_ws, size_t ws_size,
                              hipStream_t stream)
{
    const float* S   = (const float*)d_in[0];
    const void*  tgt = d_in[1];
    const void*  msk = d_in[2];
    float* out = (float*)d_out;
    float* ws  = (float*)d_ws;

    crf_chain_kernel<<<256, 256, 0, stream>>>(S, tgt, msk, ws);
    crf_reduce_kernel<<<1, 64, 0, stream>>>(ws, out);
}